// Round 4
// baseline (556.207 us; speedup 1.0000x reference)
//
#include <hip/hip_runtime.h>
#include <hip/hip_cooperative_groups.h>

namespace cg = cooperative_groups;

#define NB 8
#define NC 256
#define FH 64
#define FW 64
#define NS (FH * FW)          // 4096 spatial positions per batch
#define NSAMP 131072
#define MARGIN_F 12.0f
#define CAP 20480             // per-batch list write capacity (mean 16384, sigma~120)
#define CAPA 20544            // allocated entries per batch (CAP + read pad)
#define NCHUNK 544            // fallback gather coverage: 544*32 = 17408
#define GATHER_BLOCKS (NB * NCHUNK)   // 4352 (fallback path)
#define COOP_GRID 1024

typedef float vfloat2 __attribute__((ext_vector_type(2)));

// ---------------------------------------------------------------------------
// fp8 e4m3 (OCP) pack/unpack via gfx950 HW converts.
// ---------------------------------------------------------------------------
__device__ __forceinline__ unsigned pack4_fp8(float f0, float f1, float f2, float f3)
{
    int r = __builtin_amdgcn_cvt_pk_fp8_f32(f0, f1, 0, false);  // bytes 0,1
    r     = __builtin_amdgcn_cvt_pk_fp8_f32(f2, f3, r, true);   // bytes 2,3
    return (unsigned)r;
}

__device__ __forceinline__ void acc_u32(unsigned a, unsigned p, unsigned n, float& d)
{
    const vfloat2 a0 = __builtin_amdgcn_cvt_pk_f32_fp8(a, false);
    const vfloat2 a1 = __builtin_amdgcn_cvt_pk_f32_fp8(a, true);
    const vfloat2 p0 = __builtin_amdgcn_cvt_pk_f32_fp8(p, false);
    const vfloat2 p1 = __builtin_amdgcn_cvt_pk_f32_fp8(p, true);
    const vfloat2 n0 = __builtin_amdgcn_cvt_pk_f32_fp8(n, false);
    const vfloat2 n1 = __builtin_amdgcn_cvt_pk_f32_fp8(n, true);
    float t;
    t = a0.x - p0.x; d += t * t;  t = a0.x - n0.x; d -= t * t;
    t = a0.y - p0.y; d += t * t;  t = a0.y - n0.y; d -= t * t;
    t = a1.x - p1.x; d += t * t;  t = a1.x - n1.x; d -= t * t;
    t = a1.y - p1.y; d += t * t;  t = a1.y - n1.y; d -= t * t;
}

__device__ __forceinline__ void acc_quad(uint4 a, uint4 p, uint4 n, float& d)
{
    acc_u32(a.x, p.x, n.x, d);
    acc_u32(a.y, p.y, n.y, d);
    acc_u32(a.z, p.z, n.z, d);
    acc_u32(a.w, p.w, n.w, d);
}

// ---------------------------------------------------------------------------
// Fused cooperative kernel: 1024 blocks x 256 threads, guaranteed 4 blocks/CU
// (VGPR<=128 via launch_bounds, LDS 16.7 KB). Phases:
//   A: bucket (blocks<512, 1 window each) + transpose (4 tiles/block;
//      task&7 == bid&7 keeps XCD/batch affinity for tq/tk)
//   [threadfence + grid.sync]
//   C: static-dataflow gather (slot = bid&7 matches phase-A producer XCD),
//      grid-stride over the slot's list; masked fields -> no list memset.
//   [threadfence + grid.sync]
//   D: block 0 reduces 1024 partials -> out. No atomics, no out-zeroing.
// Launch-gap cost of 5 dispatches collapses into 2 grid.syncs.
// ---------------------------------------------------------------------------
__global__ __launch_bounds__(256, 4) void fused_all(
    const float* __restrict__ in0, const float* __restrict__ in1,
    const int*  __restrict__ batch_idx,
    const int2* __restrict__ anchor_yx,
    const int2* __restrict__ pos_yx,
    const int2* __restrict__ neg_yx,
    unsigned char* __restrict__ tq,
    unsigned char* __restrict__ tk,
    uint2* __restrict__ list,
    int*   __restrict__ cnt,        // pre-zeroed (32 B memset)
    float* __restrict__ partials,
    float* __restrict__ out)
{
    cg::grid_group grid = cg::this_grid();

    __shared__ float tile[64][65];
    __shared__ int   lcnt[NB];
    __shared__ int   lbase[NB];
    __shared__ float bsum[4];

    const int bid = blockIdx.x;
    const int t   = threadIdx.x;

    // ---------------- Phase A1: bucket (blocks 0..511) ----------------
    if (bid < 512) {
        const int i = bid * 256 + t;
        if (t < NB) lcnt[t] = 0;
        __syncthreads();
        const int b   = batch_idx[i];
        const int pos = atomicAdd(&lcnt[b], 1);
        __syncthreads();
        if (t < NB) lbase[t] = atomicAdd(&cnt[t], lcnt[t]);
        __syncthreads();

        const int2 ay = anchor_yx[i];
        const int2 py = pos_yx[i];
        const int2 ny = neg_yx[i];
        const unsigned sa = (unsigned)(ay.x * FW + ay.y);
        const unsigned sp = (unsigned)(py.x * FW + py.y);
        const unsigned sn = (unsigned)(ny.x * FW + ny.y);
        uint2 w;
        w.x = sa | (sp << 16);
        w.y = sn;
        list[(size_t)b * CAPA + lbase[b] + pos] = w;
    }

    // ---------------- Phase A2: transpose, 4 tiles per block ----------------
#pragma unroll
    for (int k = 0; k < 4; ++k) {
        const int task   = bid + k * COOP_GRID;     // task&7 == bid&7
        const int b      = task & 7;
        const int which  = (task >> 3) & 1;
        const int tile_i = task >> 4;               // 0..255
        const int s0     = (tile_i & 63) * 64;
        const int c0     = (tile_i >> 6) * 64;

        const float* __restrict__ inb =
            (which ? in1 : in0) + (size_t)b * NC * NS;
        unsigned char* __restrict__ outb =
            (which ? tk : tq) + (size_t)b * NS * NC;

        __syncthreads();   // protect tile reuse across iterations

        const int g   = t >> 4;
        const int sl4 = (t & 15) << 2;
#pragma unroll
        for (int pass = 0; pass < 4; ++pass) {
            const int cl = pass * 16 + g;
            const float4 v = *(const float4*)&inb[(size_t)(c0 + cl) * NS + (s0 + sl4)];
            tile[sl4 + 0][cl] = v.x;
            tile[sl4 + 1][cl] = v.y;
            tile[sl4 + 2][cl] = v.z;
            tile[sl4 + 3][cl] = v.w;
        }
        __syncthreads();

        const int sl = t >> 2;
        const int cg4 = (t & 3) << 4;
        uint4 w;
        w.x = pack4_fp8(tile[sl][cg4 + 0],  tile[sl][cg4 + 1],  tile[sl][cg4 + 2],  tile[sl][cg4 + 3]);
        w.y = pack4_fp8(tile[sl][cg4 + 4],  tile[sl][cg4 + 5],  tile[sl][cg4 + 6],  tile[sl][cg4 + 7]);
        w.z = pack4_fp8(tile[sl][cg4 + 8],  tile[sl][cg4 + 9],  tile[sl][cg4 + 10], tile[sl][cg4 + 11]);
        w.w = pack4_fp8(tile[sl][cg4 + 12], tile[sl][cg4 + 13], tile[sl][cg4 + 14], tile[sl][cg4 + 15]);
        *(uint4*)&outb[(size_t)(s0 + sl) * NC + (c0 + cg4)] = w;
    }

    __threadfence();
    grid.sync();

    // ---------------- Phase C: gather ----------------
    {
        const int lane = t & 63;
        const int wid  = t >> 6;
        const int hl   = t & 15;
        const int grp  = t >> 4;
        const int slot = bid & 7;          // same residue as phase-A producers
        const int jb   = bid >> 3;         // 0..127 blocks per slot

        const int count = cnt[slot];
        const uint2* __restrict__ L = list + (size_t)slot * CAPA;
        const size_t basebs = (size_t)slot * NS;
        const uint4* __restrict__ TQ = (const uint4*)tq;
        const uint4* __restrict__ TK = (const uint4*)tk;

        float acc = 0.0f;

        for (int base = jb * 32; base < count; base += 128 * 32) {
            const int i0 = base + grp;
            const int i1 = i0 + 16;

            const uint2 w0 = L[i0];        // in-bounds: i1 <= base+31 < CAPA
            const uint2 w1 = L[i1];

            const size_t a0 = (basebs + (w0.x & 0xFFFu)) * 16;
            const size_t p0 = (basebs + ((w0.x >> 16) & 0xFFFu)) * 16;
            const size_t n0 = (basebs + (w0.y & 0xFFFu)) * 16;
            const size_t a1 = (basebs + (w1.x & 0xFFFu)) * 16;
            const size_t p1 = (basebs + ((w1.x >> 16) & 0xFFFu)) * 16;
            const size_t n1 = (basebs + (w1.y & 0xFFFu)) * 16;

            const uint4 A0 = TQ[a0 + hl];
            const uint4 P0 = TK[p0 + hl];
            const uint4 N0 = TK[n0 + hl];
            const uint4 A1 = TQ[a1 + hl];
            const uint4 P1 = TK[p1 + hl];
            const uint4 N1 = TK[n1 + hl];

            float d0 = 0.0f, d1 = 0.0f;
            acc_quad(A0, P0, N0, d0);
            acc_quad(A1, P1, N1, d1);

#pragma unroll
            for (int m = 1; m < 16; m <<= 1) {
                d0 += __shfl_xor(d0, m, 64);
                d1 += __shfl_xor(d1, m, 64);
            }

            if (hl == 0) {
                if (i0 < count) acc += fmaxf(d0 + MARGIN_F, 0.0f);
                if (i1 < count) acc += fmaxf(d1 + MARGIN_F, 0.0f);
            }
        }

#pragma unroll
        for (int m = 1; m < 64; m <<= 1) acc += __shfl_xor(acc, m, 64);
        __syncthreads();   // tile/bsum reuse safety
        if (lane == 0) bsum[wid] = acc;
        __syncthreads();
        if (t == 0) partials[bid] = bsum[0] + bsum[1] + bsum[2] + bsum[3];
    }

    __threadfence();
    grid.sync();

    // ---------------- Phase D: block 0 final reduce ----------------
    if (bid == 0) {
        float s = partials[t] + partials[t + 256] + partials[t + 512] + partials[t + 768];
#pragma unroll
        for (int m = 1; m < 64; m <<= 1) s += __shfl_xor(s, m, 64);
        __syncthreads();
        if ((t & 63) == 0) bsum[t >> 6] = s;
        __syncthreads();
        if (t == 0) {
            const float invN = 1.0f / (1e-6f + (float)NSAMP);
            out[0] = (bsum[0] + bsum[1] + bsum[2] + bsum[3]) * invN;
        }
    }
}

// ===========================================================================
// Multi-dispatch fallback path (used if cooperative launch is unavailable).
// ===========================================================================

__global__ __launch_bounds__(256) void transpose_to_bsc_fp8(
    const float* __restrict__ in0, const float* __restrict__ in1,
    unsigned char* __restrict__ out0, unsigned char* __restrict__ out1)
{
    __shared__ float tile[64][65];

    const int bid    = blockIdx.x;
    const int b      = bid & 7;
    const int which  = (bid >> 3) & 1;
    const int tile_i = bid >> 4;
    const int s0     = (tile_i & 63) * 64;
    const int c0     = (tile_i >> 6) * 64;
    const int t      = threadIdx.x;

    const float* __restrict__ inb =
        (which ? in1 : in0) + (size_t)b * NC * NS;
    unsigned char* __restrict__ outb =
        (which ? out1 : out0) + (size_t)b * NS * NC;

    const int g   = t >> 4;
    const int sl4 = (t & 15) << 2;
#pragma unroll
    for (int pass = 0; pass < 4; ++pass) {
        const int cl = pass * 16 + g;
        const float4 v = *(const float4*)&inb[(size_t)(c0 + cl) * NS + (s0 + sl4)];
        tile[sl4 + 0][cl] = v.x;
        tile[sl4 + 1][cl] = v.y;
        tile[sl4 + 2][cl] = v.z;
        tile[sl4 + 3][cl] = v.w;
    }
    __syncthreads();

    const int sl = t >> 2;
    const int cg4 = (t & 3) << 4;
    uint4 w;
    w.x = pack4_fp8(tile[sl][cg4 + 0],  tile[sl][cg4 + 1],  tile[sl][cg4 + 2],  tile[sl][cg4 + 3]);
    w.y = pack4_fp8(tile[sl][cg4 + 4],  tile[sl][cg4 + 5],  tile[sl][cg4 + 6],  tile[sl][cg4 + 7]);
    w.z = pack4_fp8(tile[sl][cg4 + 8],  tile[sl][cg4 + 9],  tile[sl][cg4 + 10], tile[sl][cg4 + 11]);
    w.w = pack4_fp8(tile[sl][cg4 + 12], tile[sl][cg4 + 13], tile[sl][cg4 + 14], tile[sl][cg4 + 15]);
    *(uint4*)&outb[(size_t)(s0 + sl) * NC + (c0 + cg4)] = w;
}

__global__ __launch_bounds__(256) void bucket_samples(
    const int*  __restrict__ batch_idx,
    const int2* __restrict__ anchor_yx,
    const int2* __restrict__ pos_yx,
    const int2* __restrict__ neg_yx,
    uint2* __restrict__ list,
    int*   __restrict__ cnt)
{
    __shared__ int lcnt[NB];
    __shared__ int lbase[NB];
    const int t = threadIdx.x;
    const int i = blockIdx.x * 256 + t;

    if (t < NB) lcnt[t] = 0;
    __syncthreads();

    const int b   = batch_idx[i];
    const int pos = atomicAdd(&lcnt[b], 1);
    __syncthreads();

    if (t < NB) lbase[t] = atomicAdd(&cnt[t], lcnt[t]);
    __syncthreads();

    const int2 ay = anchor_yx[i];
    const int2 py = pos_yx[i];
    const int2 ny = neg_yx[i];
    const unsigned sa = (unsigned)(ay.x * FW + ay.y);
    const unsigned sp = (unsigned)(py.x * FW + py.y);
    const unsigned sn = (unsigned)(ny.x * FW + ny.y);

    uint2 w;
    w.x = sa | (sp << 16);
    w.y = sn;
    list[(size_t)b * CAPA + lbase[b] + pos] = w;
}

__global__ __launch_bounds__(256) void triplet_gather_fp8(
    const uint4* __restrict__ tq,
    const uint4* __restrict__ tk,
    const uint2* __restrict__ list,
    const int*  __restrict__ cnt,
    float* __restrict__ partials)
{
    const int t    = threadIdx.x;
    const int lane = t & 63;
    const int wid  = t >> 6;
    const int hl   = t & 15;
    const int grp  = t >> 4;
    const int slot = blockIdx.x & 7;
    const int j0   = blockIdx.x >> 3;

    const int count = cnt[slot];
    const uint2* __restrict__ L = list + (size_t)slot * CAPA;
    const size_t basebs = (size_t)slot * NS;

    const int i0 = j0 * 32 + grp;
    const int i1 = i0 + 16;

    const uint2 w0 = L[i0];
    const uint2 w1 = L[i1];

    const size_t a0 = (basebs + (w0.x & 0xFFFu)) * 16;
    const size_t p0 = (basebs + ((w0.x >> 16) & 0xFFFu)) * 16;
    const size_t n0 = (basebs + (w0.y & 0xFFFu)) * 16;
    const size_t a1 = (basebs + (w1.x & 0xFFFu)) * 16;
    const size_t p1 = (basebs + ((w1.x >> 16) & 0xFFFu)) * 16;
    const size_t n1 = (basebs + (w1.y & 0xFFFu)) * 16;

    const uint4 A0 = tq[a0 + hl];
    const uint4 P0 = tk[p0 + hl];
    const uint4 N0 = tk[n0 + hl];
    const uint4 A1 = tq[a1 + hl];
    const uint4 P1 = tk[p1 + hl];
    const uint4 N1 = tk[n1 + hl];

    float d0 = 0.0f, d1 = 0.0f;
    acc_quad(A0, P0, N0, d0);
    acc_quad(A1, P1, N1, d1);

#pragma unroll
    for (int m = 1; m < 16; m <<= 1) {
        d0 += __shfl_xor(d0, m, 64);
        d1 += __shfl_xor(d1, m, 64);
    }

    float acc = 0.0f;
    if (hl == 0) {
        if (i0 < count) acc += fmaxf(d0 + MARGIN_F, 0.0f);
        if (i1 < count) acc += fmaxf(d1 + MARGIN_F, 0.0f);
    }

#pragma unroll
    for (int m = 1; m < 64; m <<= 1) acc += __shfl_xor(acc, m, 64);
    __shared__ float bsum[4];
    if (lane == 0) bsum[wid] = acc;
    __syncthreads();
    if (t == 0) partials[blockIdx.x] = bsum[0] + bsum[1] + bsum[2] + bsum[3];
}

__global__ __launch_bounds__(256) void final_reduce(
    const float* __restrict__ partials, float* __restrict__ out)
{
    float s = 0.0f;
    for (int i = threadIdx.x; i < GATHER_BLOCKS; i += 256) s += partials[i];
#pragma unroll
    for (int m = 1; m < 64; m <<= 1) s += __shfl_xor(s, m, 64);
    __shared__ float ws4[4];
    if ((threadIdx.x & 63) == 0) ws4[threadIdx.x >> 6] = s;
    __syncthreads();
    if (threadIdx.x == 0) {
        const float invN = 1.0f / (1e-6f + (float)NSAMP);
        out[0] = (ws4[0] + ws4[1] + ws4[2] + ws4[3]) * invN;
    }
}

__global__ __launch_bounds__(256) void triplet_gather_fp8_compact(
    const uint4* __restrict__ tq,
    const uint4* __restrict__ tk,
    const int*  __restrict__ batch_idx,
    const int2* __restrict__ anchor_yx,
    const int2* __restrict__ pos_yx,
    const int2* __restrict__ neg_yx,
    float* __restrict__ out)
{
    const int t    = threadIdx.x;
    const int lane = t & 63;
    const int wid  = t >> 6;
    const int slot = blockIdx.x & 7;
    const int win  = blockIdx.x >> 3;
    const int s0   = win * 256;

    __shared__ int   list[256];
    __shared__ int   wtot[4];
    __shared__ float bsum[4];

    const int  b     = batch_idx[s0 + t];
    const bool match = (b == slot);
    const unsigned long long mask = __ballot(match);
    if (lane == 0) wtot[wid] = (int)__popcll(mask);
    __syncthreads();
    int off = 0;
#pragma unroll
    for (int i = 0; i < 4; ++i) off += (i < wid) ? wtot[i] : 0;
    const int count = wtot[0] + wtot[1] + wtot[2] + wtot[3];
    if (match) {
        const unsigned long long lt = (lane == 0) ? 0ull : ((1ull << lane) - 1ull);
        list[off + (int)__popcll(mask & lt)] = t;
    }
    __syncthreads();

    const int ol  = t & 7;
    const int oct = t >> 3;
    const size_t basebs = (size_t)slot * NS;
    float acc = 0.0f;

    for (int r = 0; r < count; r += 32) {
        const int idx = r + oct;
        if (idx < count) {
            const int samp = s0 + list[idx];
            const int2 ay = anchor_yx[samp];
            const int2 py = pos_yx[samp];
            const int2 ny = neg_yx[samp];

            const size_t ab = (basebs + (size_t)(ay.x * FW + ay.y)) * 16;
            const size_t pb = (basebs + (size_t)(py.x * FW + py.y)) * 16;
            const size_t nb = (basebs + (size_t)(ny.x * FW + ny.y)) * 16;

            const uint4 A0 = tq[ab + ol];
            const uint4 A1 = tq[ab + 8 + ol];
            const uint4 P0 = tk[pb + ol];
            const uint4 P1 = tk[pb + 8 + ol];
            const uint4 N0 = tk[nb + ol];
            const uint4 N1 = tk[nb + 8 + ol];

            float d = 0.0f;
            acc_quad(A0, P0, N0, d);
            acc_quad(A1, P1, N1, d);
#pragma unroll
            for (int m = 1; m < 8; m <<= 1) d += __shfl_xor(d, m, 64);
            if (ol == 0) acc += fmaxf(d + MARGIN_F, 0.0f);
        }
    }

    float s = acc;
#pragma unroll
    for (int m = 1; m < 64; m <<= 1) s += __shfl_xor(s, m, 64);
    if (lane == 0) bsum[wid] = s;
    __syncthreads();
    if (t == 0) {
        const float invN = 1.0f / (1e-6f + (float)NSAMP);
        atomicAdd(out, (bsum[0] + bsum[1] + bsum[2] + bsum[3]) * invN);
    }
}

__global__ __launch_bounds__(256) void triplet_direct(
    const float* __restrict__ q, const float* __restrict__ k,
    const int*  __restrict__ batch_idx,
    const int2* __restrict__ anchor_yx,
    const int2* __restrict__ pos_yx,
    const int2* __restrict__ neg_yx,
    float* __restrict__ out)
{
    const int lane   = threadIdx.x & 63;
    const int wid    = threadIdx.x >> 6;
    const int gwave  = blockIdx.x * 4 + wid;
    const int nwaves = gridDim.x * 4;

    float wsum = 0.0f;
    for (int i = gwave; i < NSAMP; i += nwaves) {
        const int  b  = batch_idx[i];
        const int2 ay = anchor_yx[i];
        const int2 py = pos_yx[i];
        const int2 ny = neg_yx[i];

        const size_t base = (size_t)b * NC * NS;
        const int sa = ay.x * FW + ay.y;
        const int sp = py.x * FW + py.y;
        const int sn = ny.x * FW + ny.y;

        float d = 0.0f;
#pragma unroll
        for (int kk = 0; kk < 4; ++kk) {
            const int c = lane + 64 * kk;
            const float av = q[base + (size_t)c * NS + sa];
            const float pv = k[base + (size_t)c * NS + sp];
            const float nv = k[base + (size_t)c * NS + sn];
            float tt;
            tt = av - pv; d += tt * tt;
            tt = av - nv; d -= tt * tt;
        }
#pragma unroll
        for (int m = 1; m < 64; m <<= 1) d += __shfl_xor(d, m, 64);
        if (lane == 0) wsum += fmaxf(d + MARGIN_F, 0.0f);
    }

    __shared__ float bsum[4];
    if (lane == 0) bsum[wid] = wsum;
    __syncthreads();
    if (threadIdx.x == 0) {
        const float invN = 1.0f / (1e-6f + (float)NSAMP);
        atomicAdd(out, (bsum[0] + bsum[1] + bsum[2] + bsum[3]) * invN);
    }
}

extern "C" void kernel_launch(void* const* d_in, const int* in_sizes, int n_in,
                              void* d_out, int out_size, void* d_ws, size_t ws_size,
                              hipStream_t stream)
{
    const float* sketch = (const float*)d_in[0];
    const float* refk   = (const float*)d_in[1];
    const int*   bidx   = (const int*)d_in[2];
    const int2*  ayx    = (const int2*)d_in[3];
    const int2*  pyx    = (const int2*)d_in[4];
    const int2*  nyx    = (const int2*)d_in[5];
    float*       out    = (float*)d_out;

    const size_t tensor_elems = (size_t)NB * NC * NS;                  // 8M
    const size_t need_fp8   = 2 * tensor_elems;                        // 16 MB
    const size_t list_bytes = (size_t)NB * CAPA * sizeof(uint2);       // ~1.31 MB
    const size_t part_bytes = (size_t)GATHER_BLOCKS * sizeof(float);   // covers both paths
    const size_t need_full  = need_fp8 + list_bytes + NB * sizeof(int) + part_bytes;

    if (ws_size >= need_full) {
        unsigned char* tq = (unsigned char*)d_ws;
        unsigned char* tk = tq + tensor_elems;
        uint2* list = (uint2*)(tk + tensor_elems);
        int*   cnt  = (int*)(list + (size_t)NB * CAPA);
        float* partials = (float*)(cnt + NB);

        // Only the 8 counters need zeroing (list fields are masked on read).
        (void)hipMemsetAsync(cnt, 0, NB * sizeof(int), stream);

        const float* a0 = sketch; const float* a1 = refk;
        const int* a2 = bidx;
        const int2* a3 = ayx; const int2* a4 = pyx; const int2* a5 = nyx;
        unsigned char* a6 = tq; unsigned char* a7 = tk;
        uint2* a8 = list; int* a9 = cnt; float* a10 = partials; float* a11 = out;
        void* args[] = {&a0, &a1, &a2, &a3, &a4, &a5, &a6, &a7, &a8, &a9, &a10, &a11};

        hipError_t e = hipLaunchCooperativeKernel(
            (const void*)fused_all, dim3(COOP_GRID), dim3(256), args, 0, stream);

        if (e != hipSuccess) {
            // Multi-dispatch fallback (round-3 structure, no list memset).
            bucket_samples<<<NSAMP / 256, 256, 0, stream>>>(
                bidx, ayx, pyx, nyx, list, cnt);

            transpose_to_bsc_fp8<<<4096, 256, 0, stream>>>(sketch, refk, tq, tk);

            triplet_gather_fp8<<<GATHER_BLOCKS, 256, 0, stream>>>(
                (const uint4*)tq, (const uint4*)tk, list, cnt, partials);

            final_reduce<<<1, 256, 0, stream>>>(partials, out);
        }
    } else if (ws_size >= need_fp8) {
        unsigned char* tq = (unsigned char*)d_ws;
        unsigned char* tk = tq + tensor_elems;

        (void)hipMemsetAsync(out, 0, sizeof(float), stream);

        transpose_to_bsc_fp8<<<4096, 256, 0, stream>>>(sketch, refk, tq, tk);

        triplet_gather_fp8_compact<<<4096, 256, 0, stream>>>(
            (const uint4*)tq, (const uint4*)tk, bidx, ayx, pyx, nyx, out);
    } else {
        (void)hipMemsetAsync(out, 0, sizeof(float), stream);

        triplet_direct<<<4096, 256, 0, stream>>>(
            sketch, refk, bidx, ayx, pyx, nyx, out);
    }
}

// Round 5
// 239.978 us; speedup vs baseline: 2.3177x; 2.3177x over previous
//
#include <hip/hip_runtime.h>

#define NB 8
#define NC 256
#define FH 64
#define FW 64
#define NS (FH * FW)          // 4096 spatial positions per batch
#define NSAMP 131072
#define MARGIN_F 12.0f
#define GATHER_GRID 4096      // 32 samples per block (16-lane groups, 2-deep)

typedef float vfloat2 __attribute__((ext_vector_type(2)));

// ---------------------------------------------------------------------------
// fp8 e4m3 (OCP) pack/unpack via gfx950 HW converts.
// ---------------------------------------------------------------------------
__device__ __forceinline__ unsigned pack4_fp8(float f0, float f1, float f2, float f3)
{
    int r = __builtin_amdgcn_cvt_pk_fp8_f32(f0, f1, 0, false);  // bytes 0,1
    r     = __builtin_amdgcn_cvt_pk_fp8_f32(f2, f3, r, true);   // bytes 2,3
    return (unsigned)r;
}

__device__ __forceinline__ void acc_u32(unsigned a, unsigned p, unsigned n, float& d)
{
    const vfloat2 a0 = __builtin_amdgcn_cvt_pk_f32_fp8(a, false);
    const vfloat2 a1 = __builtin_amdgcn_cvt_pk_f32_fp8(a, true);
    const vfloat2 p0 = __builtin_amdgcn_cvt_pk_f32_fp8(p, false);
    const vfloat2 p1 = __builtin_amdgcn_cvt_pk_f32_fp8(p, true);
    const vfloat2 n0 = __builtin_amdgcn_cvt_pk_f32_fp8(n, false);
    const vfloat2 n1 = __builtin_amdgcn_cvt_pk_f32_fp8(n, true);
    float t;
    t = a0.x - p0.x; d += t * t;  t = a0.x - n0.x; d -= t * t;
    t = a0.y - p0.y; d += t * t;  t = a0.y - n0.y; d -= t * t;
    t = a1.x - p1.x; d += t * t;  t = a1.x - n1.x; d -= t * t;
    t = a1.y - p1.y; d += t * t;  t = a1.y - n1.y; d -= t * t;
}

__device__ __forceinline__ void acc_quad(uint4 a, uint4 p, uint4 n, float& d)
{
    acc_u32(a.x, p.x, n.x, d);
    acc_u32(a.y, p.y, n.y, d);
    acc_u32(a.z, p.z, n.z, d);
    acc_u32(a.w, p.w, n.w, d);
}

// ---------------------------------------------------------------------------
// Dispatch 1: batched transpose (B, C, S) fp32 -> (B, S, C) fp8 e4m3.
// 64x64 tile, float4 reads, LDS fp32 tile padded to 65 (2-way alias = free),
// uint4 fp8 stores (16 B/lane). Also zero-inits the gsum/done cells used by
// the fused reduction in dispatch 2 (kernel boundary = visibility; the ws is
// re-poisoned by the harness every iteration so this must happen here).
// ---------------------------------------------------------------------------
__global__ __launch_bounds__(256) void transpose_to_bsc_fp8(
    const float* __restrict__ in0, const float* __restrict__ in1,
    unsigned char* __restrict__ out0, unsigned char* __restrict__ out1,
    float* __restrict__ gsum, unsigned* __restrict__ done)
{
    __shared__ float tile[64][65];

    const int bid    = blockIdx.x;       // 4096 = 256 tiles x 2 tensors x 8 batches
    const int b      = bid & 7;
    const int which  = (bid >> 3) & 1;
    const int tile_i = bid >> 4;         // 0..255
    const int s0     = (tile_i & 63) * 64;
    const int c0     = (tile_i >> 6) * 64;
    const int t      = threadIdx.x;

    if (bid == 0 && t == 0) { *gsum = 0.0f; *done = 0u; }

    const float* __restrict__ inb =
        (which ? in1 : in0) + (size_t)b * NC * NS;
    unsigned char* __restrict__ outb =
        (which ? out1 : out0) + (size_t)b * NS * NC;

    // ---- read: float4 along s, 16 c-rows per pass ----
    const int g   = t >> 4;          // 0..15
    const int sl4 = (t & 15) << 2;   // 0,4,...,60
#pragma unroll
    for (int pass = 0; pass < 4; ++pass) {
        const int cl = pass * 16 + g;
        const float4 v = *(const float4*)&inb[(size_t)(c0 + cl) * NS + (s0 + sl4)];
        tile[sl4 + 0][cl] = v.x;
        tile[sl4 + 1][cl] = v.y;
        tile[sl4 + 2][cl] = v.z;
        tile[sl4 + 3][cl] = v.w;
    }
    __syncthreads();

    // ---- write: 16 packed fp8 per lane (uint4), one store per thread ----
    const int sl  = t >> 2;          // 0..63 s-rows
    const int cg4 = (t & 3) << 4;    // 0,16,32,48
    uint4 w;
    w.x = pack4_fp8(tile[sl][cg4 + 0],  tile[sl][cg4 + 1],  tile[sl][cg4 + 2],  tile[sl][cg4 + 3]);
    w.y = pack4_fp8(tile[sl][cg4 + 4],  tile[sl][cg4 + 5],  tile[sl][cg4 + 6],  tile[sl][cg4 + 7]);
    w.z = pack4_fp8(tile[sl][cg4 + 8],  tile[sl][cg4 + 9],  tile[sl][cg4 + 10], tile[sl][cg4 + 11]);
    w.w = pack4_fp8(tile[sl][cg4 + 12], tile[sl][cg4 + 13], tile[sl][cg4 + 14], tile[sl][cg4 + 15]);
    *(uint4*)&outb[(size_t)(s0 + sl) * NC + (c0 + cg4)] = w;
}

// ---------------------------------------------------------------------------
// Dispatch 2: direct static-dataflow gather + fused final reduction.
// No bucketing (R2 proved the gather is latency-bound, not traffic-bound:
// affinity cut FETCH 21->8.7 MB with zero time change). 16-lane groups, one
// uint4/lane covers a 256-B vector; 2 samples per group -> 6 independent
// line-loads in flight per lane, no loop, no predicates (4096*32 == NSAMP
// exactly). Block sum -> device-scope fp atomicAdd on gsum (validated R1);
// last block (done counter) reads gsum with an agent-scope atomic load and
// writes out. All cross-block traffic goes through atomics on 2 cells.
// ---------------------------------------------------------------------------
__global__ __launch_bounds__(256) void triplet_gather_fused(
    const uint4* __restrict__ tq,   // (B*S) vectors, 16 uint4 each
    const uint4* __restrict__ tk,
    const int*  __restrict__ batch_idx,
    const int2* __restrict__ anchor_yx,
    const int2* __restrict__ pos_yx,
    const int2* __restrict__ neg_yx,
    float* __restrict__ gsum,
    unsigned* __restrict__ done,
    float* __restrict__ out)
{
    const int t    = threadIdx.x;
    const int lane = t & 63;
    const int wid  = t >> 6;
    const int hl   = t & 15;         // lane within 16-lane group
    const int grp  = t >> 4;         // 0..15 group id within block

    const int i0 = blockIdx.x * 32 + grp;   // sample ids, always < NSAMP
    const int i1 = i0 + 16;

    // ---- index loads (broadcast within the 16-lane group) ----
    const int  b0 = batch_idx[i0];
    const int  b1 = batch_idx[i1];
    const int2 ay0 = anchor_yx[i0], py0 = pos_yx[i0], ny0 = neg_yx[i0];
    const int2 ay1 = anchor_yx[i1], py1 = pos_yx[i1], ny1 = neg_yx[i1];

    const size_t base0 = (size_t)b0 * NS;
    const size_t base1 = (size_t)b1 * NS;
    const size_t a0 = (base0 + (ay0.x * FW + ay0.y)) * 16;   // uint4 units
    const size_t p0 = (base0 + (py0.x * FW + py0.y)) * 16;
    const size_t n0 = (base0 + (ny0.x * FW + ny0.y)) * 16;
    const size_t a1 = (base1 + (ay1.x * FW + ay1.y)) * 16;
    const size_t p1 = (base1 + (py1.x * FW + py1.y)) * 16;
    const size_t n1 = (base1 + (ny1.x * FW + ny1.y)) * 16;

    // ---- 6 independent 16-B loads per lane ----
    const uint4 A0 = tq[a0 + hl];
    const uint4 P0 = tk[p0 + hl];
    const uint4 N0 = tk[n0 + hl];
    const uint4 A1 = tq[a1 + hl];
    const uint4 P1 = tk[p1 + hl];
    const uint4 N1 = tk[n1 + hl];

    float d0 = 0.0f, d1 = 0.0f;
    acc_quad(A0, P0, N0, d0);
    acc_quad(A1, P1, N1, d1);

    // ---- 16-lane butterfly reductions ----
#pragma unroll
    for (int m = 1; m < 16; m <<= 1) {
        d0 += __shfl_xor(d0, m, 64);
        d1 += __shfl_xor(d1, m, 64);
    }

    float acc = 0.0f;
    if (hl == 0) {
        acc  = fmaxf(d0 + MARGIN_F, 0.0f);
        acc += fmaxf(d1 + MARGIN_F, 0.0f);
    }

    // ---- block reduction ----
#pragma unroll
    for (int m = 1; m < 64; m <<= 1) acc += __shfl_xor(acc, m, 64);
    __shared__ float bsum[4];
    if (lane == 0) bsum[wid] = acc;
    __syncthreads();

    if (t == 0) {
        const float blocksum = bsum[0] + bsum[1] + bsum[2] + bsum[3];
        atomicAdd(gsum, blocksum);          // device-scope fp atomic (R1-proven)
        __threadfence();                    // release: gsum add visible first
        const unsigned old = atomicAdd(done, 1u);
        if (old == GATHER_GRID - 1) {       // last block to finish
            __threadfence();                // acquire side
            const float g = __hip_atomic_load(gsum, __ATOMIC_ACQUIRE,
                                              __HIP_MEMORY_SCOPE_AGENT);
            const float invN = 1.0f / (1e-6f + (float)NSAMP);
            out[0] = g * invN;
        }
    }
}

// ---------------------------------------------------------------------------
// Fallback (ws too small): direct strided gather in original layout.
// ---------------------------------------------------------------------------
__global__ __launch_bounds__(256) void triplet_direct(
    const float* __restrict__ q, const float* __restrict__ k,
    const int*  __restrict__ batch_idx,
    const int2* __restrict__ anchor_yx,
    const int2* __restrict__ pos_yx,
    const int2* __restrict__ neg_yx,
    float* __restrict__ out)
{
    const int lane   = threadIdx.x & 63;
    const int wid    = threadIdx.x >> 6;
    const int gwave  = blockIdx.x * 4 + wid;
    const int nwaves = gridDim.x * 4;

    float wsum = 0.0f;
    for (int i = gwave; i < NSAMP; i += nwaves) {
        const int  b  = batch_idx[i];
        const int2 ay = anchor_yx[i];
        const int2 py = pos_yx[i];
        const int2 ny = neg_yx[i];

        const size_t base = (size_t)b * NC * NS;
        const int sa = ay.x * FW + ay.y;
        const int sp = py.x * FW + py.y;
        const int sn = ny.x * FW + ny.y;

        float d = 0.0f;
#pragma unroll
        for (int kk = 0; kk < 4; ++kk) {
            const int c = lane + 64 * kk;
            const float av = q[base + (size_t)c * NS + sa];
            const float pv = k[base + (size_t)c * NS + sp];
            const float nv = k[base + (size_t)c * NS + sn];
            float tt;
            tt = av - pv; d += tt * tt;
            tt = av - nv; d -= tt * tt;
        }
#pragma unroll
        for (int m = 1; m < 64; m <<= 1) d += __shfl_xor(d, m, 64);
        if (lane == 0) wsum += fmaxf(d + MARGIN_F, 0.0f);
    }

    __shared__ float bsum[4];
    if (lane == 0) bsum[wid] = wsum;
    __syncthreads();
    if (threadIdx.x == 0) {
        const float invN = 1.0f / (1e-6f + (float)NSAMP);
        atomicAdd(out, (bsum[0] + bsum[1] + bsum[2] + bsum[3]) * invN);
    }
}

extern "C" void kernel_launch(void* const* d_in, const int* in_sizes, int n_in,
                              void* d_out, int out_size, void* d_ws, size_t ws_size,
                              hipStream_t stream)
{
    const float* sketch = (const float*)d_in[0];
    const float* refk   = (const float*)d_in[1];
    const int*   bidx   = (const int*)d_in[2];
    const int2*  ayx    = (const int2*)d_in[3];
    const int2*  pyx    = (const int2*)d_in[4];
    const int2*  nyx    = (const int2*)d_in[5];
    float*       out    = (float*)d_out;

    const size_t tensor_elems = (size_t)NB * NC * NS;           // 8M
    const size_t need = 2 * tensor_elems + 2 * sizeof(unsigned);// 16 MB + 8 B

    if (ws_size >= need) {
        unsigned char* tq = (unsigned char*)d_ws;
        unsigned char* tk = tq + tensor_elems;
        float*    gsum = (float*)(tk + tensor_elems);
        unsigned* done = (unsigned*)(gsum + 1);

        transpose_to_bsc_fp8<<<4096, 256, 0, stream>>>(
            sketch, refk, tq, tk, gsum, done);

        triplet_gather_fused<<<GATHER_GRID, 256, 0, stream>>>(
            (const uint4*)tq, (const uint4*)tk, bidx, ayx, pyx, nyx,
            gsum, done, out);
    } else {
        (void)hipMemsetAsync(out, 0, sizeof(float), stream);

        triplet_direct<<<4096, 256, 0, stream>>>(
            sketch, refk, bidx, ayx, pyx, nyx, out);
    }
}

// Round 6
// 164.049 us; speedup vs baseline: 3.3905x; 1.4628x over previous
//
#include <hip/hip_runtime.h>

#define NB 8
#define NC 256
#define FH 64
#define FW 64
#define NS (FH * FW)          // 4096 spatial positions per batch
#define NSAMP 131072
#define MARGIN_F 12.0f
#define GATHER_GRID 4096      // 32 samples per block (8-lane octets)

typedef float vfloat2 __attribute__((ext_vector_type(2)));

// ---------------------------------------------------------------------------
// fp8 e4m3 (OCP) pack/unpack via gfx950 HW converts.
// ---------------------------------------------------------------------------
__device__ __forceinline__ unsigned pack4_fp8(float f0, float f1, float f2, float f3)
{
    int r = __builtin_amdgcn_cvt_pk_fp8_f32(f0, f1, 0, false);  // bytes 0,1
    r     = __builtin_amdgcn_cvt_pk_fp8_f32(f2, f3, r, true);   // bytes 2,3
    return (unsigned)r;
}

__device__ __forceinline__ void acc_u32(unsigned a, unsigned p, unsigned n, float& d)
{
    const vfloat2 a0 = __builtin_amdgcn_cvt_pk_f32_fp8(a, false);
    const vfloat2 a1 = __builtin_amdgcn_cvt_pk_f32_fp8(a, true);
    const vfloat2 p0 = __builtin_amdgcn_cvt_pk_f32_fp8(p, false);
    const vfloat2 p1 = __builtin_amdgcn_cvt_pk_f32_fp8(p, true);
    const vfloat2 n0 = __builtin_amdgcn_cvt_pk_f32_fp8(n, false);
    const vfloat2 n1 = __builtin_amdgcn_cvt_pk_f32_fp8(n, true);
    float t;
    t = a0.x - p0.x; d += t * t;  t = a0.x - n0.x; d -= t * t;
    t = a0.y - p0.y; d += t * t;  t = a0.y - n0.y; d -= t * t;
    t = a1.x - p1.x; d += t * t;  t = a1.x - n1.x; d -= t * t;
    t = a1.y - p1.y; d += t * t;  t = a1.y - n1.y; d -= t * t;
}

__device__ __forceinline__ void acc_quad(uint4 a, uint4 p, uint4 n, float& d)
{
    acc_u32(a.x, p.x, n.x, d);
    acc_u32(a.y, p.y, n.y, d);
    acc_u32(a.z, p.z, n.z, d);
    acc_u32(a.w, p.w, n.w, d);
}

// ---------------------------------------------------------------------------
// Dispatch 1: batched transpose (B, C, S) fp32 -> (B, S, C) fp8 e4m3.
// 64x64 tile, float4 reads, LDS fp32 tile padded to 65 (2-way alias = free),
// uint4 fp8 stores (16 B/lane). Block 0 also zeroes out[0]: kernel-end
// writeback + next-kernel acquire publishes it to the coherence point, so the
// gather's atomics accumulate onto a clean 0 (same mechanism that makes
// tq/tk visible cross-kernel). No memset dispatch needed.
// ---------------------------------------------------------------------------
__global__ __launch_bounds__(256) void transpose_to_bsc_fp8(
    const float* __restrict__ in0, const float* __restrict__ in1,
    unsigned char* __restrict__ out0, unsigned char* __restrict__ out1,
    float* __restrict__ out_scalar)
{
    __shared__ float tile[64][65];

    const int bid    = blockIdx.x;       // 4096 = 256 tiles x 2 tensors x 8 batches
    const int b      = bid & 7;
    const int which  = (bid >> 3) & 1;
    const int tile_i = bid >> 4;         // 0..255
    const int s0     = (tile_i & 63) * 64;
    const int c0     = (tile_i >> 6) * 64;
    const int t      = threadIdx.x;

    if (bid == 0 && t == 0) out_scalar[0] = 0.0f;

    const float* __restrict__ inb =
        (which ? in1 : in0) + (size_t)b * NC * NS;
    unsigned char* __restrict__ outb =
        (which ? out1 : out0) + (size_t)b * NS * NC;

    // ---- read: float4 along s, 16 c-rows per pass ----
    const int g   = t >> 4;          // 0..15
    const int sl4 = (t & 15) << 2;   // 0,4,...,60
#pragma unroll
    for (int pass = 0; pass < 4; ++pass) {
        const int cl = pass * 16 + g;
        const float4 v = *(const float4*)&inb[(size_t)(c0 + cl) * NS + (s0 + sl4)];
        tile[sl4 + 0][cl] = v.x;
        tile[sl4 + 1][cl] = v.y;
        tile[sl4 + 2][cl] = v.z;
        tile[sl4 + 3][cl] = v.w;
    }
    __syncthreads();

    // ---- write: 16 packed fp8 per lane (uint4), one store per thread ----
    const int sl  = t >> 2;          // 0..63 s-rows
    const int cg4 = (t & 3) << 4;    // 0,16,32,48
    uint4 w;
    w.x = pack4_fp8(tile[sl][cg4 + 0],  tile[sl][cg4 + 1],  tile[sl][cg4 + 2],  tile[sl][cg4 + 3]);
    w.y = pack4_fp8(tile[sl][cg4 + 4],  tile[sl][cg4 + 5],  tile[sl][cg4 + 6],  tile[sl][cg4 + 7]);
    w.z = pack4_fp8(tile[sl][cg4 + 8],  tile[sl][cg4 + 9],  tile[sl][cg4 + 10], tile[sl][cg4 + 11]);
    w.w = pack4_fp8(tile[sl][cg4 + 12], tile[sl][cg4 + 13], tile[sl][cg4 + 14], tile[sl][cg4 + 15]);
    *(uint4*)&outb[(size_t)(s0 + sl) * NC + (c0 + cg4)] = w;
}

// ---------------------------------------------------------------------------
// Dispatch 2: gather + triplet loss (R0-proven structure) + bare atomic tail.
// One sample per 8-lane octet; vector = 256 B = 16 uint4; 6 independent 16-B
// line-loads per lane issued up front. NO fences, NO flag atomics: R5 showed
// a per-block __threadfence() (agent-scope = L2 writeback+invalidate on
// non-coherent XCD L2s) destroys all L2 reuse (FETCH 21->40 MB, 35->136 us).
// A single unfenced device-scope atomicAdd per block is cheap (R1-proven,
// absmax 0.0): the RMW executes at the coherence point without touching L2.
// ---------------------------------------------------------------------------
__global__ __launch_bounds__(256) void triplet_gather_fp8(
    const uint4* __restrict__ tq,   // (B*S) vectors, 16 uint4 each
    const uint4* __restrict__ tk,
    const int*  __restrict__ batch_idx,
    const int2* __restrict__ anchor_yx,
    const int2* __restrict__ pos_yx,
    const int2* __restrict__ neg_yx,
    float* __restrict__ out)        // zeroed by dispatch 1
{
    const int t    = threadIdx.x;
    const int lane = t & 63;
    const int wid  = t >> 6;
    const int ol   = t & 7;          // lane within octet
    const int oct  = t >> 3;         // octet id within block, 0..31
    const int samp = blockIdx.x * 32 + oct;   // always < NSAMP

    const int  b  = batch_idx[samp];
    const int2 ay = anchor_yx[samp];
    const int2 py = pos_yx[samp];
    const int2 ny = neg_yx[samp];

    const size_t ab = ((size_t)(b * NS) + ay.x * FW + ay.y) * 16;  // uint4 units
    const size_t pb = ((size_t)(b * NS) + py.x * FW + py.y) * 16;
    const size_t nb = ((size_t)(b * NS) + ny.x * FW + ny.y) * 16;

    const uint4 A0 = tq[ab + ol];
    const uint4 A1 = tq[ab + 8 + ol];
    const uint4 P0 = tk[pb + ol];
    const uint4 P1 = tk[pb + 8 + ol];
    const uint4 N0 = tk[nb + ol];
    const uint4 N1 = tk[nb + 8 + ol];

    float d = 0.0f;
    acc_quad(A0, P0, N0, d);
    acc_quad(A1, P1, N1, d);

    // reduce across the 8-lane octet
#pragma unroll
    for (int m = 1; m < 8; m <<= 1) d += __shfl_xor(d, m, 64);

    // wave reduction of per-octet losses (non-ol0 lanes contribute 0)
    float acc = (ol == 0) ? fmaxf(d + MARGIN_F, 0.0f) : 0.0f;
#pragma unroll
    for (int m = 1; m < 64; m <<= 1) acc += __shfl_xor(acc, m, 64);

    __shared__ float bsum[4];
    if (lane == 0) bsum[wid] = acc;
    __syncthreads();
    if (t == 0) {
        const float invN = 1.0f / (1e-6f + (float)NSAMP);
        atomicAdd(out, (bsum[0] + bsum[1] + bsum[2] + bsum[3]) * invN);
    }
}

// ---------------------------------------------------------------------------
// Fallback (ws too small): direct strided gather in original layout.
// ---------------------------------------------------------------------------
__global__ __launch_bounds__(256) void triplet_direct(
    const float* __restrict__ q, const float* __restrict__ k,
    const int*  __restrict__ batch_idx,
    const int2* __restrict__ anchor_yx,
    const int2* __restrict__ pos_yx,
    const int2* __restrict__ neg_yx,
    float* __restrict__ out)
{
    const int lane   = threadIdx.x & 63;
    const int wid    = threadIdx.x >> 6;
    const int gwave  = blockIdx.x * 4 + wid;
    const int nwaves = gridDim.x * 4;

    float wsum = 0.0f;
    for (int i = gwave; i < NSAMP; i += nwaves) {
        const int  b  = batch_idx[i];
        const int2 ay = anchor_yx[i];
        const int2 py = pos_yx[i];
        const int2 ny = neg_yx[i];

        const size_t base = (size_t)b * NC * NS;
        const int sa = ay.x * FW + ay.y;
        const int sp = py.x * FW + py.y;
        const int sn = ny.x * FW + ny.y;

        float d = 0.0f;
#pragma unroll
        for (int kk = 0; kk < 4; ++kk) {
            const int c = lane + 64 * kk;
            const float av = q[base + (size_t)c * NS + sa];
            const float pv = k[base + (size_t)c * NS + sp];
            const float nv = k[base + (size_t)c * NS + sn];
            float tt;
            tt = av - pv; d += tt * tt;
            tt = av - nv; d -= tt * tt;
        }
#pragma unroll
        for (int m = 1; m < 64; m <<= 1) d += __shfl_xor(d, m, 64);
        if (lane == 0) wsum += fmaxf(d + MARGIN_F, 0.0f);
    }

    __shared__ float bsum[4];
    if (lane == 0) bsum[wid] = wsum;
    __syncthreads();
    if (threadIdx.x == 0) {
        const float invN = 1.0f / (1e-6f + (float)NSAMP);
        atomicAdd(out, (bsum[0] + bsum[1] + bsum[2] + bsum[3]) * invN);
    }
}

extern "C" void kernel_launch(void* const* d_in, const int* in_sizes, int n_in,
                              void* d_out, int out_size, void* d_ws, size_t ws_size,
                              hipStream_t stream)
{
    const float* sketch = (const float*)d_in[0];
    const float* refk   = (const float*)d_in[1];
    const int*   bidx   = (const int*)d_in[2];
    const int2*  ayx    = (const int2*)d_in[3];
    const int2*  pyx    = (const int2*)d_in[4];
    const int2*  nyx    = (const int2*)d_in[5];
    float*       out    = (float*)d_out;

    const size_t tensor_elems = (size_t)NB * NC * NS;   // 8M
    const size_t need = 2 * tensor_elems;               // 16 MB fp8

    if (ws_size >= need) {
        unsigned char* tq = (unsigned char*)d_ws;
        unsigned char* tk = tq + tensor_elems;

        transpose_to_bsc_fp8<<<4096, 256, 0, stream>>>(
            sketch, refk, tq, tk, out);

        triplet_gather_fp8<<<GATHER_GRID, 256, 0, stream>>>(
            (const uint4*)tq, (const uint4*)tk, bidx, ayx, pyx, nyx, out);
    } else {
        (void)hipMemsetAsync(out, 0, sizeof(float), stream);

        triplet_direct<<<4096, 256, 0, stream>>>(
            sketch, refk, bidx, ayx, pyx, nyx, out);
    }
}